// Round 5
// baseline (1254.827 us; speedup 1.0000x reference)
//
#include <hip/hip_runtime.h>
#include <hip/hip_fp16.h>

// ---------------------------------------------------------------------------
// GCN 2-layer, bucket-partitioned. Edges packed into 500 dst-range buckets
// (u64 = dst:17 | src:17 | ew:30fx). Per-bucket block aggregates into an LDS
// accumulator (200 nodes x 64 feat) with ds float atomics -> zero memory-side
// per-edge atomics, no CSR materialization. H stored fp16; math fp32.
// ---------------------------------------------------------------------------

#define NPB   200      // nodes per bucket
#define NBMAX 512
#define CAP   4096     // edges per bucket capacity (mean 3200, +15 sigma)
#define CHUNK 8192     // edges per k_bucket block

typedef unsigned long long u64;

__global__ __launch_bounds__(512) void k_init(int* gcur, float* stats) {
  int t = threadIdx.x;
  if (t < NBMAX) gcur[t] = 0;
  if (t < 256) stats[t] = 0.f;  // sums1,sumsq1,sums2,sumsq2
}

// --- Phase A: bin edges into dst-range buckets (LDS histogram, ~500 global
//     atomics per block instead of per-edge) ---
__global__ __launch_bounds__(256) void k_bucket(const int* __restrict__ ei,
                                                const float* __restrict__ ew,
                                                int* gcur, u64* __restrict__ bkt,
                                                int E, int NB) {
  __shared__ int lcnt[NBMAX];
  __shared__ int lbase[NBMAX];
  int t = threadIdx.x;
  for (int b = t; b < NBMAX; b += 256) lcnt[b] = 0;
  __syncthreads();
  int lo = blockIdx.x * CHUNK;
  int hi = min(lo + CHUNK, E);
  for (int i = lo + t; i < hi; i += 256)
    atomicAdd(&lcnt[ei[E + i] / NPB], 1);
  __syncthreads();
  for (int b = t; b < NB; b += 256) {
    int c = lcnt[b];
    lbase[b] = c ? atomicAdd(&gcur[b], c) : 0;
    lcnt[b] = 0;
  }
  __syncthreads();
  for (int i = lo + t; i < hi; i += 256) {
    int src = ei[i], dst = ei[E + i];
    float w = ew[i];
    int b = dst / NPB;
    int pos = lbase[b] + atomicAdd(&lcnt[b], 1);
    if (pos < CAP) {
      unsigned wq = (unsigned)(w * 1073741824.0f);
      if (wq > 0x3FFFFFFFu) wq = 0x3FFFFFFFu;
      bkt[(size_t)b * CAP + pos] =
          ((u64)(unsigned)dst << 47) | ((u64)(unsigned)src << 30) | (u64)wq;
    }
  }
}

// --- deg/dinv: per-bucket LDS accumulation, no global atomics ---
__global__ __launch_bounds__(256) void k_deg(const u64* __restrict__ bkt,
                                             const int* __restrict__ gcur,
                                             float* __restrict__ dinv, int N) {
  __shared__ float deg[NPB];
  int b = blockIdx.x, t = threadIdx.x;
  for (int n = t; n < NPB; n += 256) deg[n] = 0.f;
  __syncthreads();
  int cnt = min(gcur[b], CAP);
  size_t base = (size_t)b * CAP;
  for (int i = t; i < cnt; i += 256) {
    u64 u = bkt[base + i];
    int dl = (int)(u >> 47) - b * NPB;
    float w = (float)(unsigned)(u & 0x3FFFFFFFu) * (1.0f / 1073741824.0f);
    atomicAdd(&deg[dl], w);
  }
  __syncthreads();
  for (int n = t; n < NPB; n += 256) {
    int gn = b * NPB + n;
    if (gn < N) dinv[gn] = rsqrtf(deg[n] + 1.0f);  // +1 self-loop
  }
}

__device__ inline unsigned pk2(float a, float b) {
  __half2 h = __floats2half2_rn(a, b);
  return *reinterpret_cast<unsigned*>(&h);
}

// --- GEMM: Y[N][64](fp16) = act(X[N][64]) @ W[64][64]; FUSE = BN+ReLU on X ---
template <int FUSE>
__global__ __launch_bounds__(256) void k_gemm(const float* __restrict__ X,
                                              const float* __restrict__ W,
                                              __half* __restrict__ Y, int N,
                                              const float* __restrict__ scale,
                                              const float* __restrict__ shift) {
  __shared__ float Wl[64 * 64];
  __shared__ float sc[64], sh[64];
  int tid = threadIdx.x;
  {
    float4* Wl4 = (float4*)Wl;
    const float4* W4 = (const float4*)W;
#pragma unroll
    for (int i = 0; i < 4; ++i) Wl4[tid + i * 256] = W4[tid + i * 256];
  }
  if (FUSE && tid < 64) { sc[tid] = scale[tid]; sh[tid] = shift[tid]; }
  __syncthreads();
  int row = blockIdx.x * 64 + (tid >> 2);
  if (row >= N) return;
  int c0 = (tid & 3) * 16;
  float4 a0 = make_float4(0.f, 0.f, 0.f, 0.f), a1 = a0, a2 = a0, a3 = a0;
  const float4* Xr = (const float4*)(X + (size_t)row * 64);
#pragma unroll
  for (int kk = 0; kk < 16; ++kk) {
    float4 xv = Xr[kk];
    if (FUSE) {
      int k4 = kk * 4;
      xv.x = fmaxf(fmaf(xv.x, sc[k4 + 0], sh[k4 + 0]), 0.f);
      xv.y = fmaxf(fmaf(xv.y, sc[k4 + 1], sh[k4 + 1]), 0.f);
      xv.z = fmaxf(fmaf(xv.z, sc[k4 + 2], sh[k4 + 2]), 0.f);
      xv.w = fmaxf(fmaf(xv.w, sc[k4 + 3], sh[k4 + 3]), 0.f);
    }
    const float* wbase = &Wl[(kk * 4) * 64 + c0];
#pragma unroll
    for (int d = 0; d < 4; ++d) {
      float xk = (d == 0) ? xv.x : (d == 1) ? xv.y : (d == 2) ? xv.z : xv.w;
      const float4* Wr = (const float4*)(wbase + d * 64);
      float4 w0 = Wr[0], w1 = Wr[1], w2 = Wr[2], w3 = Wr[3];
      a0.x = fmaf(xk, w0.x, a0.x); a0.y = fmaf(xk, w0.y, a0.y);
      a0.z = fmaf(xk, w0.z, a0.z); a0.w = fmaf(xk, w0.w, a0.w);
      a1.x = fmaf(xk, w1.x, a1.x); a1.y = fmaf(xk, w1.y, a1.y);
      a1.z = fmaf(xk, w1.z, a1.z); a1.w = fmaf(xk, w1.w, a1.w);
      a2.x = fmaf(xk, w2.x, a2.x); a2.y = fmaf(xk, w2.y, a2.y);
      a2.z = fmaf(xk, w2.z, a2.z); a2.w = fmaf(xk, w2.w, a2.w);
      a3.x = fmaf(xk, w3.x, a3.x); a3.y = fmaf(xk, w3.y, a3.y);
      a3.z = fmaf(xk, w3.z, a3.z); a3.w = fmaf(xk, w3.w, a3.w);
    }
  }
  uint4 p0, p1;
  p0.x = pk2(a0.x, a0.y); p0.y = pk2(a0.z, a0.w);
  p0.z = pk2(a1.x, a1.y); p0.w = pk2(a1.z, a1.w);
  p1.x = pk2(a2.x, a2.y); p1.y = pk2(a2.z, a2.w);
  p1.z = pk2(a3.x, a3.y); p1.w = pk2(a3.z, a3.w);
  uint4* Y4 = (uint4*)(Y + (size_t)row * 64 + c0);
  Y4[0] = p0; Y4[1] = p1;
}

// --- fused aggregation: per-bucket LDS accumulator, 8-deep gather pipeline,
//     BN partials fused ---
__global__ __launch_bounds__(512, 4) void k_agg_f(const __half* __restrict__ H,
                                                  const u64* __restrict__ bkt,
                                                  const int* __restrict__ gcur,
                                                  const float* __restrict__ dinv,
                                                  const float* __restrict__ bias,
                                                  float* __restrict__ out,
                                                  float* __restrict__ sums,
                                                  float* __restrict__ sumsq,
                                                  int N) {
  __shared__ float acc[NPB * 64];   // 51.2 KB
  __shared__ float dv[NPB];
  __shared__ float red[2][8][64];
  int t = threadIdx.x, lane = t & 63, wv = t >> 6;  // 8 waves
  int b = blockIdx.x;
  for (int i = t; i < NPB * 64; i += 512) acc[i] = 0.f;
  for (int n = t; n < NPB; n += 512) {
    int gn = b * NPB + n;
    dv[n] = (gn < N) ? dinv[gn] : 0.f;
  }
  __syncthreads();
  int cnt = min(gcur[b], CAP);
  size_t base = (size_t)b * CAP;
  for (int e0 = wv * 8; e0 < cnt; e0 += 64) {
    u64 u[8]; int sidx[8]; int dl[8]; float wt[8];
#pragma unroll
    for (int i = 0; i < 8; ++i) {
      int idx = e0 + i;
      u[i] = (idx < cnt) ? bkt[base + idx] : 0ULL;
    }
#pragma unroll
    for (int i = 0; i < 8; ++i) {
      bool ok = (u[i] != 0ULL);
      sidx[i] = (int)((u[i] >> 30) & 0x1FFFFu);
      int d = (int)(u[i] >> 47) - b * NPB;
      dl[i] = ok ? d : 0;
      float ww = (float)(unsigned)(u[i] & 0x3FFFFFFFu) * (1.0f / 1073741824.0f);
      wt[i] = ok ? ww * dinv[sidx[i]] * dv[dl[i]] : 0.f;
    }
    float hv[8];
#pragma unroll
    for (int i = 0; i < 8; ++i)
      hv[i] = __half2float(H[(size_t)sidx[i] * 64 + lane]);
#pragma unroll
    for (int i = 0; i < 8; ++i)
      atomicAdd(&acc[dl[i] * 64 + lane], wt[i] * hv[i]);
  }
  __syncthreads();
  float ssum = 0.f, ssq = 0.f;
  float bia = bias[lane];
  for (int n = wv; n < NPB; n += 8) {
    int gn = b * NPB + n;
    if (gn >= N) break;
    float di = dv[n];
    float hn = __half2float(H[(size_t)gn * 64 + lane]);
    float v = acc[n * 64 + lane] + di * di * hn + bia;
    out[(size_t)gn * 64 + lane] = v;
    ssum += v;
    ssq = fmaf(v, v, ssq);
  }
  red[0][wv][lane] = ssum;
  red[1][wv][lane] = ssq;
  __syncthreads();
  if (wv == 0) {
    float a = 0.f, c = 0.f;
#pragma unroll
    for (int k = 0; k < 8; ++k) { a += red[0][k][lane]; c += red[1][k][lane]; }
    atomicAdd(&sums[lane], a);
    atomicAdd(&sumsq[lane], c);
  }
}

__global__ __launch_bounds__(64) void k_finalize(const float* __restrict__ sums,
                                                 const float* __restrict__ sumsq,
                                                 const float* __restrict__ gamma,
                                                 const float* __restrict__ beta,
                                                 float* __restrict__ scale,
                                                 float* __restrict__ shift, float invN) {
  int t = threadIdx.x;
  if (t < 64) {
    float mean = sums[t] * invN;
    float var = sumsq[t] * invN - mean * mean;
    float sc = gamma[t] * rsqrtf(var + 1e-5f);
    scale[t] = sc;
    shift[t] = fmaf(-mean, sc, beta[t]);
  }
}

__global__ __launch_bounds__(256) void k_bnrelu(float* __restrict__ Y,
                                                const float* __restrict__ scale,
                                                const float* __restrict__ shift, int n4) {
  int i = blockIdx.x * 256 + threadIdx.x;
  if (i >= n4) return;
  float4 v = ((float4*)Y)[i];
  int f = (i & 15) * 4;
  v.x = fmaxf(fmaf(v.x, scale[f + 0], shift[f + 0]), 0.f);
  v.y = fmaxf(fmaf(v.y, scale[f + 1], shift[f + 1]), 0.f);
  v.z = fmaxf(fmaf(v.z, scale[f + 2], shift[f + 2]), 0.f);
  v.w = fmaxf(fmaf(v.w, scale[f + 3], shift[f + 3]), 0.f);
  ((float4*)Y)[i] = v;
}

extern "C" void kernel_launch(void* const* d_in, const int* in_sizes, int n_in,
                              void* d_out, int out_size, void* d_ws, size_t ws_size,
                              hipStream_t stream) {
  const float* x   = (const float*)d_in[0];
  const int*   ei  = (const int*)d_in[1];
  const float* ew  = (const float*)d_in[2];
  const float* W1  = (const float*)d_in[3];
  const float* b1  = (const float*)d_in[4];
  const float* g1  = (const float*)d_in[5];
  const float* be1 = (const float*)d_in[6];
  const float* W2  = (const float*)d_in[7];
  const float* b2  = (const float*)d_in[8];
  const float* g2  = (const float*)d_in[9];
  const float* be2 = (const float*)d_in[10];
  int N = in_sizes[0] / 64;
  int E = in_sizes[1] / 2;
  float* out = (float*)d_out;

  int NB = (N + NPB - 1) / NPB;  // 500

  char* ws = (char*)d_ws;
  size_t off = 0;
  auto alloc = [&](size_t bytes) {
    char* p = ws + off;
    off = (off + bytes + 255) & ~(size_t)255;
    return p;
  };

  int*    gcur  = (int*)alloc(NBMAX * 4);
  float*  dinv  = (float*)alloc((size_t)N * 4);
  __half* h1    = (__half*)alloc((size_t)N * 64 * 2);
  float*  stats = (float*)alloc(256 * 4);
  float*  scsh  = (float*)alloc(256 * 4);
  u64*    bkt   = (u64*)alloc((size_t)NB * CAP * 8);

  float *sums1 = stats, *sumsq1 = stats + 64, *sums2 = stats + 128, *sumsq2 = stats + 192;
  float *scale1 = scsh, *shift1 = scsh + 64, *scale2 = scsh + 128, *shift2 = scsh + 192;

  k_init<<<1, 512, 0, stream>>>(gcur, stats);
  k_bucket<<<(E + CHUNK - 1) / CHUNK, 256, 0, stream>>>(ei, ew, gcur, bkt, E, NB);
  k_deg<<<NB, 256, 0, stream>>>(bkt, gcur, dinv, N);

  // layer 1: gemm -> fused agg (d_out as temp) -> finalize
  k_gemm<0><<<(N + 63) / 64, 256, 0, stream>>>(x, W1, h1, N, nullptr, nullptr);
  k_agg_f<<<NB, 512, 0, stream>>>(h1, bkt, gcur, dinv, b1, out, sums1, sumsq1, N);
  k_finalize<<<1, 64, 0, stream>>>(sums1, sumsq1, g1, be1, scale1, shift1, 1.0f / N);

  // layer 2: gemm (BN+ReLU fused on input) -> fused agg -> finalize -> bnrelu
  k_gemm<1><<<(N + 63) / 64, 256, 0, stream>>>(out, W2, h1, N, scale1, shift1);
  k_agg_f<<<NB, 512, 0, stream>>>(h1, bkt, gcur, dinv, b2, out, sums2, sumsq2, N);
  k_finalize<<<1, 64, 0, stream>>>(sums2, sumsq2, g2, be2, scale2, shift2, 1.0f / N);
  k_bnrelu<<<(N * 16 + 255) / 256, 256, 0, stream>>>(out, scale2, shift2, N * 16);
}

// Round 6
// 307.119 us; speedup vs baseline: 4.0858x; 4.0858x over previous
//
#include <hip/hip_runtime.h>
#include <hip/hip_fp16.h>

// ---------------------------------------------------------------------------
// GCN 2-layer. Edges binned into 500 dst-range buckets (u64 = dst:17|src:17|
// ew_q30), then per-bucket counting-sort in LDS (int atomics only -> native
// ds_add_u32) producing an 8-padded dst-sorted CSR + dinv. Aggregation is the
// proven pull kernel: register accumulate, 8-deep gather ILP, no atomics.
// H stored fp16; math fp32. NO float LDS atomics anywhere (CAS-loop trap).
// ---------------------------------------------------------------------------

#define NPB   200      // nodes per bucket
#define NBMAX 512
#define CAP   5120     // padded entries per bucket (mean ~3900, ~19 sigma)
#define CHUNK 8192     // edges per k_bucket block

typedef unsigned long long u64;

__global__ __launch_bounds__(512) void k_init(int* gcur, float* stats) {
  int t = threadIdx.x;
  if (t < NBMAX) gcur[t] = 0;
  if (t < 256) stats[t] = 0.f;  // sums1,sumsq1,sums2,sumsq2
}

// --- Phase A: bin edges into dst-range buckets (LDS int histogram) ---
__global__ __launch_bounds__(256) void k_bucket(const int* __restrict__ ei,
                                                const float* __restrict__ ew,
                                                int* gcur, u64* __restrict__ bkt,
                                                int E, int NB) {
  __shared__ int lcnt[NBMAX];
  __shared__ int lbase[NBMAX];
  int t = threadIdx.x;
  for (int b = t; b < NBMAX; b += 256) lcnt[b] = 0;
  __syncthreads();
  int lo = blockIdx.x * CHUNK;
  int hi = min(lo + CHUNK, E);
  for (int i = lo + t; i < hi; i += 256)
    atomicAdd(&lcnt[ei[E + i] / NPB], 1);
  __syncthreads();
  for (int b = t; b < NB; b += 256) {
    int c = lcnt[b];
    lbase[b] = c ? atomicAdd(&gcur[b], c) : 0;
    lcnt[b] = 0;
  }
  __syncthreads();
  for (int i = lo + t; i < hi; i += 256) {
    int src = ei[i], dst = ei[E + i];
    float w = ew[i];
    int b = dst / NPB;
    int pos = lbase[b] + atomicAdd(&lcnt[b], 1);
    if (pos < CAP) {
      unsigned wq = (unsigned)(w * 1073741824.0f);
      if (wq > 0x3FFFFFFFu) wq = 0x3FFFFFFFu;
      bkt[(size_t)b * CAP + pos] =
          ((u64)(unsigned)dst << 47) | ((u64)(unsigned)src << 30) | (u64)wq;
    }
  }
}

// --- Phase B: per-bucket counting-sort in LDS -> padded dst-sorted CSR,
//     deg/dinv via 4-lane shuffle sums (no FP atomics anywhere) ---
__global__ __launch_bounds__(256) void k_sort(const u64* __restrict__ bkt,
                                              const int* __restrict__ gcur,
                                              float2* __restrict__ csr,
                                              int2* __restrict__ row,
                                              float* __restrict__ dinv, int N) {
  __shared__ u64 sorted[CAP];       // 40 KB
  __shared__ int hist[256];
  __shared__ int offs[256];
  __shared__ int cur[NPB];
  __shared__ int cpArr[NPB];
  __shared__ float dv[NPB];
  int b = blockIdx.x, t = threadIdx.x;
  for (int i = t; i < CAP; i += 256) sorted[i] = 0ULL;
  hist[t] = 0;
  if (t < NPB) cur[t] = 0;
  __syncthreads();
  int cnt = min(gcur[b], CAP);
  size_t base = (size_t)b * CAP;
  for (int i = t; i < cnt; i += 256) {
    int dl = (int)(bkt[base + i] >> 47) - b * NPB;
    atomicAdd(&hist[dl], 1);           // int LDS atomic: native ds_add_u32
  }
  __syncthreads();
  int c = (t < NPB) ? ((hist[t] + 7) & ~7) : 0;  // pad each node to mult of 8
  offs[t] = c;
  __syncthreads();
  for (int o = 1; o < 256; o <<= 1) {  // Hillis-Steele inclusive scan
    int x = (t >= o) ? offs[t - o] : 0;
    __syncthreads();
    offs[t] += x;
    __syncthreads();
  }
  int total = offs[255];
  int myoff = offs[t] - c;             // exclusive
  __syncthreads();
  offs[t] = myoff;
  if (t < NPB) cpArr[t] = c;
  __syncthreads();
  // scatter into LDS padded-sorted layout
  for (int i = t; i < cnt; i += 256) {
    u64 u = bkt[base + i];
    int dl = (int)(u >> 47) - b * NPB;
    int pos = offs[dl] + atomicAdd(&cur[dl], 1);
    if (pos < CAP) sorted[pos] = u;
  }
  __syncthreads();
  // deg/dinv: 4 lanes per node summing its contiguous LDS segment (pads = 0)
  for (int q = t; q < NPB * 4; q += 256) {
    int n = q >> 2, s = q & 3;
    int o = offs[n], cp = cpArr[n];
    float sum = 0.f;
    for (int j = o + s; j < o + cp; j += 4)
      sum += (float)(unsigned)(sorted[j] & 0x3FFFFFFFu);
    sum += __shfl_xor(sum, 1);
    sum += __shfl_xor(sum, 2);
    if (s == 0) {
      float d = rsqrtf(sum * (1.0f / 1073741824.0f) + 1.0f);  // +1 self-loop
      dv[n] = d;
      int gn = b * NPB + n;
      if (gn < N) dinv[gn] = d;
    }
  }
  __syncthreads();
  // write CSR (dinv_dst folded into weight) + row descriptors
  int totalC = min(total, CAP);
  for (int j = t; j < totalC; j += 256) {
    u64 u = sorted[j];
    unsigned wq = (unsigned)(u & 0x3FFFFFFFu);
    int dl = (int)(u >> 47) - b * NPB;
    int dlc = (wq == 0) ? 0 : dl;      // pads decode to dl<0 but have wq==0
    float w = (float)wq * (1.0f / 1073741824.0f) * dv[dlc];
    int s = (int)((u >> 30) & 0x1FFFFu);
    csr[base + j] = make_float2(__int_as_float(s), w);
  }
  for (int n = t; n < NPB; n += 256) {
    int gn = b * NPB + n;
    if (gn < N) {
      int o = offs[n];
      int cp = min(cpArr[n], max(0, CAP - o)) & ~7;
      row[gn] = make_int2((int)(base + o), cp);
    }
  }
}

__device__ inline unsigned pk2(float a, float b) {
  __half2 h = __floats2half2_rn(a, b);
  return *reinterpret_cast<unsigned*>(&h);
}

// --- GEMM: Y[N][64](fp16) = act(X[N][64]) @ W[64][64]; FUSE = BN+ReLU on X ---
template <int FUSE>
__global__ __launch_bounds__(256) void k_gemm(const float* __restrict__ X,
                                              const float* __restrict__ W,
                                              __half* __restrict__ Y, int N,
                                              const float* __restrict__ scale,
                                              const float* __restrict__ shift) {
  __shared__ float Wl[64 * 64];
  __shared__ float sc[64], sh[64];
  int tid = threadIdx.x;
  {
    float4* Wl4 = (float4*)Wl;
    const float4* W4 = (const float4*)W;
#pragma unroll
    for (int i = 0; i < 4; ++i) Wl4[tid + i * 256] = W4[tid + i * 256];
  }
  if (FUSE && tid < 64) { sc[tid] = scale[tid]; sh[tid] = shift[tid]; }
  __syncthreads();
  int row = blockIdx.x * 64 + (tid >> 2);
  if (row >= N) return;
  int c0 = (tid & 3) * 16;
  float4 a0 = make_float4(0.f, 0.f, 0.f, 0.f), a1 = a0, a2 = a0, a3 = a0;
  const float4* Xr = (const float4*)(X + (size_t)row * 64);
#pragma unroll
  for (int kk = 0; kk < 16; ++kk) {
    float4 xv = Xr[kk];
    if (FUSE) {
      int k4 = kk * 4;
      xv.x = fmaxf(fmaf(xv.x, sc[k4 + 0], sh[k4 + 0]), 0.f);
      xv.y = fmaxf(fmaf(xv.y, sc[k4 + 1], sh[k4 + 1]), 0.f);
      xv.z = fmaxf(fmaf(xv.z, sc[k4 + 2], sh[k4 + 2]), 0.f);
      xv.w = fmaxf(fmaf(xv.w, sc[k4 + 3], sh[k4 + 3]), 0.f);
    }
    const float* wbase = &Wl[(kk * 4) * 64 + c0];
#pragma unroll
    for (int d = 0; d < 4; ++d) {
      float xk = (d == 0) ? xv.x : (d == 1) ? xv.y : (d == 2) ? xv.z : xv.w;
      const float4* Wr = (const float4*)(wbase + d * 64);
      float4 w0 = Wr[0], w1 = Wr[1], w2 = Wr[2], w3 = Wr[3];
      a0.x = fmaf(xk, w0.x, a0.x); a0.y = fmaf(xk, w0.y, a0.y);
      a0.z = fmaf(xk, w0.z, a0.z); a0.w = fmaf(xk, w0.w, a0.w);
      a1.x = fmaf(xk, w1.x, a1.x); a1.y = fmaf(xk, w1.y, a1.y);
      a1.z = fmaf(xk, w1.z, a1.z); a1.w = fmaf(xk, w1.w, a1.w);
      a2.x = fmaf(xk, w2.x, a2.x); a2.y = fmaf(xk, w2.y, a2.y);
      a2.z = fmaf(xk, w2.z, a2.z); a2.w = fmaf(xk, w2.w, a2.w);
      a3.x = fmaf(xk, w3.x, a3.x); a3.y = fmaf(xk, w3.y, a3.y);
      a3.z = fmaf(xk, w3.z, a3.z); a3.w = fmaf(xk, w3.w, a3.w);
    }
  }
  uint4 p0, p1;
  p0.x = pk2(a0.x, a0.y); p0.y = pk2(a0.z, a0.w);
  p0.z = pk2(a1.x, a1.y); p0.w = pk2(a1.z, a1.w);
  p1.x = pk2(a2.x, a2.y); p1.y = pk2(a2.z, a2.w);
  p1.z = pk2(a3.x, a3.y); p1.w = pk2(a3.z, a3.w);
  uint4* Y4 = (uint4*)(Y + (size_t)row * 64 + c0);
  Y4[0] = p0; Y4[1] = p1;
}

// --- pull aggregation: register accumulate, tail-free 8-deep gather ILP ---
__global__ __launch_bounds__(256) void k_agg(const __half* __restrict__ H,
                                             const int2* __restrict__ row,
                                             const float2* __restrict__ csr,
                                             const float* __restrict__ dinv,
                                             const float* __restrict__ bias,
                                             float* __restrict__ out,
                                             float* __restrict__ sums,
                                             float* __restrict__ sumsq, int N) {
  int lane = threadIdx.x & 63;
  int wib = threadIdx.x >> 6;
  int wid = blockIdx.x * 4 + wib;
  int nw = gridDim.x * 4;
  float b = bias[lane];
  float ssum = 0.f, ssq = 0.f;
  for (int n = wid; n < N; n += nw) {
    int2 r = row[n];
    size_t base = (size_t)r.x;
    int cntp = r.y;  // multiple of 8, pads have w=0
    float di = dinv[n];
    float hn = __half2float(H[(size_t)n * 64 + lane]);
    float acc0 = 0.f, acc1 = 0.f, acc2 = 0.f, acc3 = 0.f;
    const float4* c4 = (const float4*)(csr + base);
    for (int j = 0; j < cntp; j += 8) {
      float4 q0 = c4[(j >> 1) + 0], q1 = c4[(j >> 1) + 1];
      float4 q2 = c4[(j >> 1) + 2], q3 = c4[(j >> 1) + 3];
      int s0 = __float_as_int(q0.x), s1 = __float_as_int(q0.z);
      int s2 = __float_as_int(q1.x), s3 = __float_as_int(q1.z);
      int s4 = __float_as_int(q2.x), s5 = __float_as_int(q2.z);
      int s6 = __float_as_int(q3.x), s7 = __float_as_int(q3.z);
      float w0 = q0.y * dinv[s0], w1 = q0.w * dinv[s1];
      float w2 = q1.y * dinv[s2], w3 = q1.w * dinv[s3];
      float w4 = q2.y * dinv[s4], w5 = q2.w * dinv[s5];
      float w6 = q3.y * dinv[s6], w7 = q3.w * dinv[s7];
      float h0 = __half2float(H[(size_t)s0 * 64 + lane]);
      float h1 = __half2float(H[(size_t)s1 * 64 + lane]);
      float h2 = __half2float(H[(size_t)s2 * 64 + lane]);
      float h3 = __half2float(H[(size_t)s3 * 64 + lane]);
      float h4 = __half2float(H[(size_t)s4 * 64 + lane]);
      float h5 = __half2float(H[(size_t)s5 * 64 + lane]);
      float h6 = __half2float(H[(size_t)s6 * 64 + lane]);
      float h7 = __half2float(H[(size_t)s7 * 64 + lane]);
      acc0 = fmaf(w0, h0, acc0); acc1 = fmaf(w1, h1, acc1);
      acc2 = fmaf(w2, h2, acc2); acc3 = fmaf(w3, h3, acc3);
      acc0 = fmaf(w4, h4, acc0); acc1 = fmaf(w5, h5, acc1);
      acc2 = fmaf(w6, h6, acc2); acc3 = fmaf(w7, h7, acc3);
    }
    // csr weights already include dinv_dst
    float v = (acc0 + acc1) + (acc2 + acc3) + di * di * hn + b;
    out[(size_t)n * 64 + lane] = v;
    ssum += v;
    ssq = fmaf(v, v, ssq);
  }
  __shared__ float ls[4][64];
  __shared__ float ls2[4][64];
  ls[wib][lane] = ssum; ls2[wib][lane] = ssq;
  __syncthreads();
  if (wib == 0) {
    float a = ls[0][lane] + ls[1][lane] + ls[2][lane] + ls[3][lane];
    float c = ls2[0][lane] + ls2[1][lane] + ls2[2][lane] + ls2[3][lane];
    atomicAdd(&sums[lane], a);
    atomicAdd(&sumsq[lane], c);
  }
}

__global__ __launch_bounds__(64) void k_finalize(const float* __restrict__ sums,
                                                 const float* __restrict__ sumsq,
                                                 const float* __restrict__ gamma,
                                                 const float* __restrict__ beta,
                                                 float* __restrict__ scale,
                                                 float* __restrict__ shift, float invN) {
  int t = threadIdx.x;
  if (t < 64) {
    float mean = sums[t] * invN;
    float var = sumsq[t] * invN - mean * mean;
    float sc = gamma[t] * rsqrtf(var + 1e-5f);
    scale[t] = sc;
    shift[t] = fmaf(-mean, sc, beta[t]);
  }
}

__global__ __launch_bounds__(256) void k_bnrelu(float* __restrict__ Y,
                                                const float* __restrict__ scale,
                                                const float* __restrict__ shift, int n4) {
  int i = blockIdx.x * 256 + threadIdx.x;
  if (i >= n4) return;
  float4 v = ((float4*)Y)[i];
  int f = (i & 15) * 4;
  v.x = fmaxf(fmaf(v.x, scale[f + 0], shift[f + 0]), 0.f);
  v.y = fmaxf(fmaf(v.y, scale[f + 1], shift[f + 1]), 0.f);
  v.z = fmaxf(fmaf(v.z, scale[f + 2], shift[f + 2]), 0.f);
  v.w = fmaxf(fmaf(v.w, scale[f + 3], shift[f + 3]), 0.f);
  ((float4*)Y)[i] = v;
}

extern "C" void kernel_launch(void* const* d_in, const int* in_sizes, int n_in,
                              void* d_out, int out_size, void* d_ws, size_t ws_size,
                              hipStream_t stream) {
  const float* x   = (const float*)d_in[0];
  const int*   ei  = (const int*)d_in[1];
  const float* ew  = (const float*)d_in[2];
  const float* W1  = (const float*)d_in[3];
  const float* b1  = (const float*)d_in[4];
  const float* g1  = (const float*)d_in[5];
  const float* be1 = (const float*)d_in[6];
  const float* W2  = (const float*)d_in[7];
  const float* b2  = (const float*)d_in[8];
  const float* g2  = (const float*)d_in[9];
  const float* be2 = (const float*)d_in[10];
  int N = in_sizes[0] / 64;
  int E = in_sizes[1] / 2;
  float* out = (float*)d_out;

  int NB = (N + NPB - 1) / NPB;  // 500

  char* ws = (char*)d_ws;
  size_t off = 0;
  auto alloc = [&](size_t bytes) {
    char* p = ws + off;
    off = (off + bytes + 255) & ~(size_t)255;
    return p;
  };

  int*    gcur  = (int*)alloc(NBMAX * 4);
  float*  dinv  = (float*)alloc((size_t)N * 4);
  __half* h1    = (__half*)alloc((size_t)N * 64 * 2);
  float*  stats = (float*)alloc(256 * 4);
  float*  scsh  = (float*)alloc(256 * 4);
  int2*   row   = (int2*)alloc((size_t)N * 8);
  u64*    bkt   = (u64*)alloc((size_t)NB * CAP * 8);
  float2* csr   = (float2*)alloc((size_t)NB * CAP * 8);

  float *sums1 = stats, *sumsq1 = stats + 64, *sums2 = stats + 128, *sumsq2 = stats + 192;
  float *scale1 = scsh, *shift1 = scsh + 64, *scale2 = scsh + 128, *shift2 = scsh + 192;

  k_init<<<1, 512, 0, stream>>>(gcur, stats);
  k_bucket<<<(E + CHUNK - 1) / CHUNK, 256, 0, stream>>>(ei, ew, gcur, bkt, E, NB);
  k_sort<<<NB, 256, 0, stream>>>(bkt, gcur, csr, row, dinv, N);

  // layer 1: gemm -> agg (d_out as temp) -> finalize
  k_gemm<0><<<(N + 63) / 64, 256, 0, stream>>>(x, W1, h1, N, nullptr, nullptr);
  k_agg<<<2048, 256, 0, stream>>>(h1, row, csr, dinv, b1, out, sums1, sumsq1, N);
  k_finalize<<<1, 64, 0, stream>>>(sums1, sumsq1, g1, be1, scale1, shift1, 1.0f / N);

  // layer 2: gemm (BN+ReLU fused on input) -> agg -> finalize -> bnrelu
  k_gemm<1><<<(N + 63) / 64, 256, 0, stream>>>(out, W2, h1, N, scale1, shift1);
  k_agg<<<2048, 256, 0, stream>>>(h1, row, csr, dinv, b2, out, sums2, sumsq2, N);
  k_finalize<<<1, 64, 0, stream>>>(sums2, sumsq2, g2, be2, scale2, shift2, 1.0f / N);
  k_bnrelu<<<(N * 16 + 255) / 256, 256, 0, stream>>>(out, scale2, shift2, N * 16);
}

// Round 8
// 302.232 us; speedup vs baseline: 4.1519x; 1.0162x over previous
//
#include <hip/hip_runtime.h>
#include <hip/hip_fp16.h>

// ---------------------------------------------------------------------------
// GCN 2-layer. Edges binned into 500 dst-range buckets (u64 = dst:17|src:17|
// ew_q30), per-bucket LDS counting-sort (int atomics only) -> 8-padded
// dst-sorted u32 CSR {src:17|w_q15:15} with dinv_dst folded; k_fold folds
// dinv_src. Pull aggregation: 2 uint4 + 8 H-gathers per 8-edge batch, no
// per-edge atomics, nt hints protect H residency in L2. H fp16; math fp32.
// ---------------------------------------------------------------------------

#define NPB   200      // nodes per bucket
#define NBMAX 512
#define CAP   5120     // padded entries per bucket
#define CHUNK 8192     // edges per k_bucket block

typedef unsigned long long u64;
typedef unsigned int u32;
typedef u32 u32x4 __attribute__((ext_vector_type(4)));

__global__ __launch_bounds__(512) void k_init(int* gcur, float* stats) {
  int t = threadIdx.x;
  if (t < NBMAX) gcur[t] = 0;
  if (t < 256) stats[t] = 0.f;  // sums1,sumsq1,sums2,sumsq2
}

// --- Phase A: bin edges into dst-range buckets (LDS int histogram) ---
__global__ __launch_bounds__(256) void k_bucket(const int* __restrict__ ei,
                                                const float* __restrict__ ew,
                                                int* gcur, u64* __restrict__ bkt,
                                                int E, int NB) {
  __shared__ int lcnt[NBMAX];
  __shared__ int lbase[NBMAX];
  int t = threadIdx.x;
  for (int b = t; b < NBMAX; b += 256) lcnt[b] = 0;
  __syncthreads();
  int lo = blockIdx.x * CHUNK;
  int hi = min(lo + CHUNK, E);
  for (int i = lo + t; i < hi; i += 256)
    atomicAdd(&lcnt[ei[E + i] / NPB], 1);
  __syncthreads();
  for (int b = t; b < NB; b += 256) {
    int c = lcnt[b];
    lbase[b] = c ? atomicAdd(&gcur[b], c) : 0;
    lcnt[b] = 0;
  }
  __syncthreads();
  for (int i = lo + t; i < hi; i += 256) {
    int src = ei[i], dst = ei[E + i];
    float w = ew[i];
    int b = dst / NPB;
    int pos = lbase[b] + atomicAdd(&lcnt[b], 1);
    if (pos < CAP) {
      unsigned wq = (unsigned)(w * 1073741824.0f);
      if (wq > 0x3FFFFFFFu) wq = 0x3FFFFFFFu;
      bkt[(size_t)b * CAP + pos] =
          ((u64)(unsigned)dst << 47) | ((u64)(unsigned)src << 30) | (u64)wq;
    }
  }
}

// --- Phase B: per-bucket counting-sort in LDS -> padded dst-sorted u32 CSR
//     (w = ew*dinv_dst, q15), deg/dinv via shuffle sums. No FP atomics. ---
__global__ __launch_bounds__(256) void k_sort(const u64* __restrict__ bkt,
                                              const int* __restrict__ gcur,
                                              u32* __restrict__ csr,
                                              int2* __restrict__ row,
                                              float* __restrict__ dinv, int N) {
  __shared__ u64 sorted[CAP];       // 40 KB
  __shared__ int hist[256];
  __shared__ int offs[256];
  __shared__ int cur[NPB];
  __shared__ int cpArr[NPB];
  __shared__ float dv[NPB];
  int b = blockIdx.x, t = threadIdx.x;
  for (int i = t; i < CAP; i += 256) sorted[i] = 0ULL;
  hist[t] = 0;
  if (t < NPB) cur[t] = 0;
  __syncthreads();
  int cnt = min(gcur[b], CAP);
  size_t base = (size_t)b * CAP;
  for (int i = t; i < cnt; i += 256) {
    int dl = (int)(bkt[base + i] >> 47) - b * NPB;
    atomicAdd(&hist[dl], 1);           // int LDS atomic: native ds_add_u32
  }
  __syncthreads();
  int c = (t < NPB) ? ((hist[t] + 7) & ~7) : 0;  // pad each node to mult of 8
  offs[t] = c;
  __syncthreads();
  for (int o = 1; o < 256; o <<= 1) {  // Hillis-Steele inclusive scan
    int x = (t >= o) ? offs[t - o] : 0;
    __syncthreads();
    offs[t] += x;
    __syncthreads();
  }
  int total = offs[255];
  int myoff = offs[t] - c;             // exclusive
  __syncthreads();
  offs[t] = myoff;
  if (t < NPB) cpArr[t] = c;
  __syncthreads();
  // scatter into LDS padded-sorted layout
  for (int i = t; i < cnt; i += 256) {
    u64 u = bkt[base + i];
    int dl = (int)(u >> 47) - b * NPB;
    int pos = offs[dl] + atomicAdd(&cur[dl], 1);
    if (pos < CAP) sorted[pos] = u;
  }
  __syncthreads();
  // deg/dinv: 4 lanes per node summing its contiguous LDS segment (pads = 0)
  for (int q = t; q < NPB * 4; q += 256) {
    int n = q >> 2, s = q & 3;
    int o = offs[n], cp = cpArr[n];
    float sum = 0.f;
    for (int j = o + s; j < o + cp; j += 4)
      sum += (float)(unsigned)(sorted[j] & 0x3FFFFFFFu);
    sum += __shfl_xor(sum, 1);
    sum += __shfl_xor(sum, 2);
    if (s == 0) {
      float d = rsqrtf(sum * (1.0f / 1073741824.0f) + 1.0f);  // +1 self-loop
      dv[n] = d;
      int gn = b * NPB + n;
      if (gn < N) dinv[gn] = d;
    }
  }
  __syncthreads();
  // write u32 CSR (dinv_dst folded, q15) + row descriptors
  int totalC = min(total, CAP);
  for (int j = t; j < totalC; j += 256) {
    u64 u = sorted[j];
    unsigned wq = (unsigned)(u & 0x3FFFFFFFu);
    int dl = (int)(u >> 47) - b * NPB;
    int dlc = (wq == 0) ? 0 : dl;      // pads decode to dl<0 but have wq==0
    float w = (float)wq * (1.0f / 1073741824.0f) * dv[dlc];
    unsigned q15 = (unsigned)(w * 32768.0f + 0.5f);
    if (q15 > 32767u) q15 = 32767u;
    unsigned s = (unsigned)((u >> 30) & 0x1FFFFu);
    csr[base + j] = (s << 15) | q15;
  }
  for (int n = t; n < NPB; n += 256) {
    int gn = b * NPB + n;
    if (gn < N) {
      int o = offs[n];
      int cp = min(cpArr[n], max(0, CAP - o)) & ~7;
      row[gn] = make_int2((int)(base + o), cp);
    }
  }
}

// --- fold dinv[src] into csr weights (one gather per edge, amortized) ---
__global__ __launch_bounds__(256) void k_fold(u32* __restrict__ csr,
                                              const float* __restrict__ dinv,
                                              int total4, int N) {
  int i = blockIdx.x * 256 + threadIdx.x;
  if (i >= total4) return;
  uint4 q = ((uint4*)csr)[i];
#pragma unroll
  for (int k = 0; k < 4; ++k) {
    u32 u = (&q.x)[k];
    int s = (int)(u >> 15);
    float d = dinv[min(s, N - 1)];
    unsigned nq = (unsigned)((float)(u & 0x7FFFu) * d + 0.5f);
    (&q.x)[k] = (u & 0xFFFF8000u) | nq;
  }
  ((uint4*)csr)[i] = q;
}

__device__ inline unsigned pk2(float a, float b) {
  __half2 h = __floats2half2_rn(a, b);
  return *reinterpret_cast<unsigned*>(&h);
}

// --- GEMM: Y[N][64](fp16) = act(X[N][64]) @ W[64][64]; FUSE = BN+ReLU on X ---
template <int FUSE>
__global__ __launch_bounds__(256) void k_gemm(const float* __restrict__ X,
                                              const float* __restrict__ W,
                                              __half* __restrict__ Y, int N,
                                              const float* __restrict__ scale,
                                              const float* __restrict__ shift) {
  __shared__ float Wl[64 * 64];
  __shared__ float sc[64], sh[64];
  int tid = threadIdx.x;
  {
    float4* Wl4 = (float4*)Wl;
    const float4* W4 = (const float4*)W;
#pragma unroll
    for (int i = 0; i < 4; ++i) Wl4[tid + i * 256] = W4[tid + i * 256];
  }
  if (FUSE && tid < 64) { sc[tid] = scale[tid]; sh[tid] = shift[tid]; }
  __syncthreads();
  int row = blockIdx.x * 64 + (tid >> 2);
  if (row >= N) return;
  int c0 = (tid & 3) * 16;
  float4 a0 = make_float4(0.f, 0.f, 0.f, 0.f), a1 = a0, a2 = a0, a3 = a0;
  const float4* Xr = (const float4*)(X + (size_t)row * 64);
#pragma unroll
  for (int kk = 0; kk < 16; ++kk) {
    float4 xv = Xr[kk];
    if (FUSE) {
      int k4 = kk * 4;
      xv.x = fmaxf(fmaf(xv.x, sc[k4 + 0], sh[k4 + 0]), 0.f);
      xv.y = fmaxf(fmaf(xv.y, sc[k4 + 1], sh[k4 + 1]), 0.f);
      xv.z = fmaxf(fmaf(xv.z, sc[k4 + 2], sh[k4 + 2]), 0.f);
      xv.w = fmaxf(fmaf(xv.w, sc[k4 + 3], sh[k4 + 3]), 0.f);
    }
    const float* wbase = &Wl[(kk * 4) * 64 + c0];
#pragma unroll
    for (int d = 0; d < 4; ++d) {
      float xk = (d == 0) ? xv.x : (d == 1) ? xv.y : (d == 2) ? xv.z : xv.w;
      const float4* Wr = (const float4*)(wbase + d * 64);
      float4 w0 = Wr[0], w1 = Wr[1], w2 = Wr[2], w3 = Wr[3];
      a0.x = fmaf(xk, w0.x, a0.x); a0.y = fmaf(xk, w0.y, a0.y);
      a0.z = fmaf(xk, w0.z, a0.z); a0.w = fmaf(xk, w0.w, a0.w);
      a1.x = fmaf(xk, w1.x, a1.x); a1.y = fmaf(xk, w1.y, a1.y);
      a1.z = fmaf(xk, w1.z, a1.z); a1.w = fmaf(xk, w1.w, a1.w);
      a2.x = fmaf(xk, w2.x, a2.x); a2.y = fmaf(xk, w2.y, a2.y);
      a2.z = fmaf(xk, w2.z, a2.z); a2.w = fmaf(xk, w2.w, a2.w);
      a3.x = fmaf(xk, w3.x, a3.x); a3.y = fmaf(xk, w3.y, a3.y);
      a3.z = fmaf(xk, w3.z, a3.z); a3.w = fmaf(xk, w3.w, a3.w);
    }
  }
  uint4 p0, p1;
  p0.x = pk2(a0.x, a0.y); p0.y = pk2(a0.z, a0.w);
  p0.z = pk2(a1.x, a1.y); p0.w = pk2(a1.z, a1.w);
  p1.x = pk2(a2.x, a2.y); p1.y = pk2(a2.z, a2.w);
  p1.z = pk2(a3.x, a3.y); p1.w = pk2(a3.z, a3.w);
  uint4* Y4 = (uint4*)(Y + (size_t)row * 64 + c0);
  Y4[0] = p0; Y4[1] = p1;
}

// --- pull aggregation: 2 uint4 + 8 H-gathers per 8-edge batch, weights fully
//     prefolded (q15), nt hints keep H resident in L2 ---
__global__ __launch_bounds__(256) void k_agg(const __half* __restrict__ H,
                                             const int2* __restrict__ row,
                                             const u32* __restrict__ csr,
                                             const float* __restrict__ dinv,
                                             const float* __restrict__ bias,
                                             float* __restrict__ out,
                                             float* __restrict__ sums,
                                             float* __restrict__ sumsq, int N) {
  const float QS = 1.0f / 32768.0f;
  int lane = threadIdx.x & 63;
  int wib = threadIdx.x >> 6;
  int wid = blockIdx.x * 4 + wib;
  int nw = gridDim.x * 4;
  float b = bias[lane];
  float ssum = 0.f, ssq = 0.f;
  for (int n = wid; n < N; n += nw) {
    int2 r = row[n];
    const u32x4* c4 = (const u32x4*)(csr + r.x);
    int cntp = r.y;  // multiple of 8, pads have w=0
    float di = dinv[n];
    float hn = __half2float(H[(size_t)n * 64 + lane]);
    float acc0 = 0.f, acc1 = 0.f, acc2 = 0.f, acc3 = 0.f;
    for (int j = 0; j < cntp; j += 8) {
      u32x4 qa = __builtin_nontemporal_load(&c4[(j >> 2) + 0]);
      u32x4 qb = __builtin_nontemporal_load(&c4[(j >> 2) + 1]);
      int s0 = (int)(qa.x >> 15), s1 = (int)(qa.y >> 15);
      int s2 = (int)(qa.z >> 15), s3 = (int)(qa.w >> 15);
      int s4 = (int)(qb.x >> 15), s5 = (int)(qb.y >> 15);
      int s6 = (int)(qb.z >> 15), s7 = (int)(qb.w >> 15);
      float w0 = (float)(qa.x & 0x7FFFu) * QS, w1 = (float)(qa.y & 0x7FFFu) * QS;
      float w2 = (float)(qa.z & 0x7FFFu) * QS, w3 = (float)(qa.w & 0x7FFFu) * QS;
      float w4 = (float)(qb.x & 0x7FFFu) * QS, w5 = (float)(qb.y & 0x7FFFu) * QS;
      float w6 = (float)(qb.z & 0x7FFFu) * QS, w7 = (float)(qb.w & 0x7FFFu) * QS;
      float h0 = __half2float(H[(size_t)s0 * 64 + lane]);
      float h1 = __half2float(H[(size_t)s1 * 64 + lane]);
      float h2 = __half2float(H[(size_t)s2 * 64 + lane]);
      float h3 = __half2float(H[(size_t)s3 * 64 + lane]);
      float h4 = __half2float(H[(size_t)s4 * 64 + lane]);
      float h5 = __half2float(H[(size_t)s5 * 64 + lane]);
      float h6 = __half2float(H[(size_t)s6 * 64 + lane]);
      float h7 = __half2float(H[(size_t)s7 * 64 + lane]);
      acc0 = fmaf(w0, h0, acc0); acc1 = fmaf(w1, h1, acc1);
      acc2 = fmaf(w2, h2, acc2); acc3 = fmaf(w3, h3, acc3);
      acc0 = fmaf(w4, h4, acc0); acc1 = fmaf(w5, h5, acc1);
      acc2 = fmaf(w6, h6, acc2); acc3 = fmaf(w7, h7, acc3);
    }
    float v = (acc0 + acc1) + (acc2 + acc3) + di * di * hn + b;
    __builtin_nontemporal_store(v, &out[(size_t)n * 64 + lane]);
    ssum += v;
    ssq = fmaf(v, v, ssq);
  }
  __shared__ float ls[4][64];
  __shared__ float ls2[4][64];
  ls[wib][lane] = ssum; ls2[wib][lane] = ssq;
  __syncthreads();
  if (wib == 0) {
    float a = ls[0][lane] + ls[1][lane] + ls[2][lane] + ls[3][lane];
    float c = ls2[0][lane] + ls2[1][lane] + ls2[2][lane] + ls2[3][lane];
    atomicAdd(&sums[lane], a);
    atomicAdd(&sumsq[lane], c);
  }
}

__global__ __launch_bounds__(64) void k_finalize(const float* __restrict__ sums,
                                                 const float* __restrict__ sumsq,
                                                 const float* __restrict__ gamma,
                                                 const float* __restrict__ beta,
                                                 float* __restrict__ scale,
                                                 float* __restrict__ shift, float invN) {
  int t = threadIdx.x;
  if (t < 64) {
    float mean = sums[t] * invN;
    float var = sumsq[t] * invN - mean * mean;
    float sc = gamma[t] * rsqrtf(var + 1e-5f);
    scale[t] = sc;
    shift[t] = fmaf(-mean, sc, beta[t]);
  }
}

__global__ __launch_bounds__(256) void k_bnrelu(float* __restrict__ Y,
                                                const float* __restrict__ scale,
                                                const float* __restrict__ shift, int n4) {
  int i = blockIdx.x * 256 + threadIdx.x;
  if (i >= n4) return;
  float4 v = ((float4*)Y)[i];
  int f = (i & 15) * 4;
  v.x = fmaxf(fmaf(v.x, scale[f + 0], shift[f + 0]), 0.f);
  v.y = fmaxf(fmaf(v.y, scale[f + 1], shift[f + 1]), 0.f);
  v.z = fmaxf(fmaf(v.z, scale[f + 2], shift[f + 2]), 0.f);
  v.w = fmaxf(fmaf(v.w, scale[f + 3], shift[f + 3]), 0.f);
  ((float4*)Y)[i] = v;
}

extern "C" void kernel_launch(void* const* d_in, const int* in_sizes, int n_in,
                              void* d_out, int out_size, void* d_ws, size_t ws_size,
                              hipStream_t stream) {
  const float* x   = (const float*)d_in[0];
  const int*   ei  = (const int*)d_in[1];
  const float* ew  = (const float*)d_in[2];
  const float* W1  = (const float*)d_in[3];
  const float* b1  = (const float*)d_in[4];
  const float* g1  = (const float*)d_in[5];
  const float* be1 = (const float*)d_in[6];
  const float* W2  = (const float*)d_in[7];
  const float* b2  = (const float*)d_in[8];
  const float* g2  = (const float*)d_in[9];
  const float* be2 = (const float*)d_in[10];
  int N = in_sizes[0] / 64;
  int E = in_sizes[1] / 2;
  float* out = (float*)d_out;

  int NB = (N + NPB - 1) / NPB;  // 500

  char* ws = (char*)d_ws;
  size_t off = 0;
  auto alloc = [&](size_t bytes) {
    char* p = ws + off;
    off = (off + bytes + 255) & ~(size_t)255;
    return p;
  };

  int*    gcur  = (int*)alloc(NBMAX * 4);
  float*  dinv  = (float*)alloc((size_t)N * 4);
  __half* h1    = (__half*)alloc((size_t)N * 64 * 2);
  float*  stats = (float*)alloc(256 * 4);
  float*  scsh  = (float*)alloc(256 * 4);
  int2*   row   = (int2*)alloc((size_t)N * 8);
  u64*    bkt   = (u64*)alloc((size_t)NB * CAP * 8);
  u32*    csr   = (u32*)alloc((size_t)NB * CAP * 4);

  float *sums1 = stats, *sumsq1 = stats + 64, *sums2 = stats + 128, *sumsq2 = stats + 192;
  float *scale1 = scsh, *shift1 = scsh + 64, *scale2 = scsh + 128, *shift2 = scsh + 192;

  int total4 = NB * CAP / 4;

  k_init<<<1, 512, 0, stream>>>(gcur, stats);
  k_bucket<<<(E + CHUNK - 1) / CHUNK, 256, 0, stream>>>(ei, ew, gcur, bkt, E, NB);
  k_sort<<<NB, 256, 0, stream>>>(bkt, gcur, csr, row, dinv, N);
  k_fold<<<(total4 + 255) / 256, 256, 0, stream>>>(csr, dinv, total4, N);

  // layer 1: gemm -> agg (d_out as temp) -> finalize
  k_gemm<0><<<(N + 63) / 64, 256, 0, stream>>>(x, W1, h1, N, nullptr, nullptr);
  k_agg<<<2048, 256, 0, stream>>>(h1, row, csr, dinv, b1, out, sums1, sumsq1, N);
  k_finalize<<<1, 64, 0, stream>>>(sums1, sumsq1, g1, be1, scale1, shift1, 1.0f / N);

  // layer 2: gemm (BN+ReLU fused on input) -> agg -> finalize -> bnrelu
  k_gemm<1><<<(N + 63) / 64, 256, 0, stream>>>(out, W2, h1, N, scale1, shift1);
  k_agg<<<2048, 256, 0, stream>>>(h1, row, csr, dinv, b2, out, sums2, sumsq2, N);
  k_finalize<<<1, 64, 0, stream>>>(sums2, sumsq2, g2, be2, scale2, shift2, 1.0f / N);
  k_bnrelu<<<(N * 16 + 255) / 256, 256, 0, stream>>>(out, scale2, shift2, N * 16);
}